// Round 1
// baseline (859.891 us; speedup 1.0000x reference)
//
#include <hip/hip_runtime.h>
#include <math.h>

#define FHh 480
#define FWw 640
#define NPIX (FHh*FWw)          // 307200
#define NSEMC 16
#define COBS 20
#define MAPC 480
#define VRc 100
#define HZc 80
#define MINZc 13
#define MAXZc 25
#define ZW 12
#define NB 4
#define NBINS_DIM 101
#define NBINS_ROW 101
#define COUNTS_PAD 40960        // per array, 1024*40 >= 40804
#define BANDMAX 600000          // est. band points ~283K; 2.1x margin
#define NTOT (NB*NPIX)          // 1,228,800

// ---------------- pose + affine params ----------------
__global__ void pose_kernel(const float* __restrict__ pose_obs,
                            const float* __restrict__ poses_last,
                            float* __restrict__ out_p1,
                            float* __restrict__ out_p2,
                            float* __restrict__ params)
{
    int b = threadIdx.x;
    if (b >= NB) return;
    float pl0 = poses_last[b*3+0], pl1 = poses_last[b*3+1], pl2 = poses_last[b*3+2];
    float po0 = pose_obs[b*3+0],  po1 = pose_obs[b*3+1],  po2 = pose_obs[b*3+2];
    const float DEGf = 57.29577951308232f;
    float t0 = pl2 / DEGf;
    float s = sinf(t0), c = cosf(t0);
    float y_new = pl1 + po0*s + po1*c;
    float x_new = pl0 + po0*c - po1*s;
    float t_new = pl2 + po2*DEGf;
    t_new = fmodf(t_new - 180.0f, 360.0f) + 180.0f;
    t_new = fmodf(t_new + 180.0f, 360.0f) - 180.0f;
    out_p1[b*3+0]=x_new; out_p1[b*3+1]=y_new; out_p1[b*3+2]=t_new;
    out_p2[b*3+0]=x_new; out_p2[b*3+1]=y_new; out_p2[b*3+2]=t_new;
    float sx = -(((x_new*100.0f)/5.0f - 240.0f)/240.0f);
    float sy = -(((y_new*100.0f)/5.0f - 240.0f)/240.0f);
    float st_t = (90.0f - t_new) * 0.017453292519943295f;
    params[b*4+0] = cosf(st_t);
    params[b*4+1] = sinf(st_t);
    params[b*4+2] = sx;
    params[b*4+3] = sy;
}

// ---------------- per-pixel projection math ----------------
__device__ __forceinline__ float4 pixel_pos(const float* __restrict__ obsb,
                                            const float* __restrict__ sh,
                                            int b, int n, float fconst)
{
    int col = n % FWw, row = n / FWw;
    float depth = obsb[3*NPIX + n];
    const float4 s4 = ((const float4*)sh)[(size_t)b*NPIX + n];
    float sm = (((s4.x + s4.y) + s4.z) + s4.w) / 4.0f;
    float factor = 1.0f + sm;

    float X = ((float)col - 319.5f) * depth / fconst;
    float Z = ((float)(FHh-1-row) - 239.5f) * depth / fconst;
    float x_s = X + 250.0f;
    float z_s = Z + 88.0f;
    float xn = (x_s/5.0f - 50.0f)/100.0f*2.0f;
    float yn = (depth/5.0f - 50.0f)/100.0f*2.0f;
    float zn = (z_s/5.0f - 32.0f)/80.0f*2.0f;
    xn = fminf(fmaxf(xn,-1.0f),1.0f);
    yn = fminf(fmaxf(yn,-1.0f),1.0f);
    zn = fminf(fmaxf(zn,-1.0f),1.0f);
    float pos0 = (xn*100.0f)/2.0f + 50.0f;
    float pos1 = (yn*100.0f)/2.0f + 50.0f;
    float pos2 = (zn*80.0f)/2.0f + 40.0f;
    return make_float4(pos0, pos1, pos2, factor);
}

// A dim contributes iff some tap p with weight>0 lies in (0, GD).
__device__ __forceinline__ bool dim_ok(float p, int GD)
{
    int f = (int)floorf(p);
    float fr = p - (float)f;
    bool t0 = (f > 0) && (f < GD);          // weight 1-fr > 0 always (fr < 1)
    bool t1 = (f + 1 < GD) && (fr > 0.0f);  // f+1 > 0 always (p >= 0)
    return t0 || t1;
}

// ---------------- pass A: bin counting + predicate ----------------
__global__ void bin_count_kernel(const float* __restrict__ obs,
                                 const float* __restrict__ sh,
                                 int* __restrict__ auxBid,
                                 int* __restrict__ counts,
                                 int* __restrict__ countsB,
                                 float fconst)
{
    int g = blockIdx.x*blockDim.x + threadIdx.x;
    if (g >= NTOT) return;
    int b = g / NPIX, n = g % NPIX;
    const float* obsb = obs + (size_t)b*COBS*NPIX;
    float4 P = pixel_pos(obsb, sh, b, n, fconst);

    bool ok = dim_ok(P.x, VRc) && dim_ok(P.y, VRc) && dim_ok(P.z, HZc);
    if (!ok) { auxBid[g] = -1; return; }

    int f0 = (int)floorf(P.x);   // in [0,99] after filter
    int f1 = (int)floorf(P.y);   // in [0,99]
    int bid = (b*NBINS_DIM + f0)*NBINS_ROW + f1;
    atomicAdd(&counts[bid], 1);
    bool band = (P.z > 12.0f) && (P.z < 25.0f);
    if (band) atomicAdd(&countsB[bid], 1);
    auxBid[g] = band ? (bid | (1<<30)) : bid;
}

// ---------------- exclusive scan (+copy) over one padded counts array ----------------
// layout at base: [counts | offsetsWork | countsB | offsetsWorkB], each COUNTS_PAD
__global__ void scan_kernel(int* __restrict__ base)
{
    int* cnt = base + (size_t)blockIdx.x * 2 * COUNTS_PAD;
    int* wrk = cnt + COUNTS_PAD;
    __shared__ int part[1024];
    int t = threadIdx.x;
    const int CHUNK = COUNTS_PAD / 1024;   // 40
    int bo = t*CHUNK;
    int s = 0;
    for (int k = 0; k < CHUNK; ++k) s += cnt[bo+k];
    part[t] = s;
    __syncthreads();
    for (int off = 1; off < 1024; off <<= 1) {
        int v = (t >= off) ? part[t-off] : 0;
        __syncthreads();
        part[t] += v;
        __syncthreads();
    }
    int run = part[t] - s;   // exclusive base for this chunk
    for (int k = 0; k < CHUNK; ++k) {
        int c = cnt[bo+k];
        cnt[bo+k] = run;
        wrk[bo+k] = run;
        run += c;
    }
}

// ---------------- pass C: counting-sort scatter + semantic packing ----------------
__global__ void scatter_kernel(const float* __restrict__ obs,
                               const float* __restrict__ sh,
                               const int* __restrict__ auxBid,
                               int* __restrict__ offsetsWork,
                               int* __restrict__ offsetsWorkB,
                               float4* __restrict__ payloadPos,
                               float4* __restrict__ bandPos,
                               float4* __restrict__ bandSem,
                               float fconst)
{
    int g = blockIdx.x*blockDim.x + threadIdx.x;
    if (g >= NTOT) return;
    int v = auxBid[g];
    if (v < 0) return;
    int bid  = v & 0x3FFFFFFF;
    bool band = (v >> 30) & 1;

    int b = g / NPIX, n = g % NPIX;
    const float* obsb = obs + (size_t)b*COBS*NPIX;
    float4 P = pixel_pos(obsb, sh, b, n, fconst);

    int dst = atomicAdd(&offsetsWork[bid], 1);
    payloadPos[dst] = P;

    if (band) {
        int dstB = atomicAdd(&offsetsWorkB[bid], 1);
        if (dstB < BANDMAX) {
            bandPos[dstB] = P;
            float4* bs = bandSem + (size_t)dstB*4;
            #pragma unroll
            for (int q = 0; q < 4; ++q) {
                float4 e;
                e.x = obsb[(4 + 4*q + 0)*NPIX + n] * P.w;
                e.y = obsb[(4 + 4*q + 1)*NPIX + n] * P.w;
                e.z = obsb[(4 + 4*q + 2)*NPIX + n] * P.w;
                e.w = obsb[(4 + 4*q + 3)*NPIX + n] * P.w;
                bs[q] = e;
            }
        }
    }
}

// ---------------- pass B: gather, two binned streams ----------------
__global__ __launch_bounds__(128)
void gather_kernel(const float4* __restrict__ payloadPos,
                   const int* __restrict__ offsets,
                   const float4* __restrict__ bandPos,
                   const float4* __restrict__ bandSem,
                   const int* __restrict__ offsetsB,
                   float* __restrict__ avwin,
                   float* __restrict__ fp_out)
{
    int cell = blockIdx.x;          // j*100 + i
    int b = blockIdx.y;
    int tid = threadIdx.x;
    int i = cell % VRc, j = cell / VRc;

    __shared__ float acc[HZc + NSEMC*ZW];   // 272 floats
    for (int k = tid; k < HZc + NSEMC*ZW; k += 128) acc[k] = 0.0f;
    __syncthreads();

    if (i > 0 && j > 0) {
        #pragma unroll
        for (int fi = 0; fi < 2; ++fi) {
            int f0r = i - 1 + fi;
            int rb = (b*NBINS_DIM + f0r)*NBINS_ROW;
            // ---- all-points stream: occupancy accumulation ----
            int s = offsets[rb + j - 1];
            int e = offsets[rb + j + 1];
            for (int idx = s + tid; idx < e; idx += 128) {
                float4 P = payloadPos[idx];
                float wx = 1.0f - fabsf(P.x - (float)i);
                float wy = 1.0f - fabsf(P.y - (float)j);
                float wxy = wx * wy;
                if (wxy <= 0.0f) continue;
                int qA = (int)floorf(P.z), qB = qA + 1;
                float fz = P.z - (float)qA;
                if (qA > 0 && qA < HZc) {
                    float w = wxy * (1.0f - fz);
                    if (w > 0.0f) atomicAdd(&acc[qA], P.w * w);
                }
                if (qB > 0 && qB < HZc) {
                    float w = wxy * fz;
                    if (w > 0.0f) atomicAdd(&acc[qB], P.w * w);
                }
            }
            // ---- band stream: semantic accumulation ----
            int sB = offsetsB[rb + j - 1];
            int eB = offsetsB[rb + j + 1];
            for (int idx = sB + tid; idx < eB; idx += 128) {
                float4 P = bandPos[idx];
                float wx = 1.0f - fabsf(P.x - (float)i);
                float wy = 1.0f - fabsf(P.y - (float)j);
                float wxy = wx * wy;
                if (wxy <= 0.0f) continue;
                int qA = (int)floorf(P.z), qB = qA + 1;
                float fz = P.z - (float)qA;
                float w0 = (qA >= MINZc && qA < MAXZc) ? wxy * (1.0f - fz) : 0.0f;
                float w1 = (qB >= MINZc && qB < MAXZc) ? wxy * fz          : 0.0f;
                if (w0 <= 0.0f && w1 <= 0.0f) continue;
                float4 s0 = bandSem[(size_t)idx*4 + 0];
                float4 s1 = bandSem[(size_t)idx*4 + 1];
                float4 s2 = bandSem[(size_t)idx*4 + 2];
                float4 s3 = bandSem[(size_t)idx*4 + 3];
                float ev[16] = { s0.x,s0.y,s0.z,s0.w, s1.x,s1.y,s1.z,s1.w,
                                 s2.x,s2.y,s2.z,s2.w, s3.x,s3.y,s3.z,s3.w };
                if (w0 > 0.0f) {
                    int zA = qA - MINZc;
                    #pragma unroll
                    for (int c = 0; c < NSEMC; ++c)
                        atomicAdd(&acc[HZc + c*ZW + zA], ev[c] * w0);
                }
                if (w1 > 0.0f) {
                    int zB = qB - MINZc;
                    #pragma unroll
                    for (int c = 0; c < NSEMC; ++c)
                        atomicAdd(&acc[HZc + c*ZW + zB], ev[c] * w1);
                }
            }
        }
    }
    __syncthreads();

    float* avb = avwin + (size_t)b*18*10000;
    if (tid < NSEMC) {
        float sum = 0.0f;
        #pragma unroll
        for (int z = 0; z < ZW; ++z) sum += rintf(acc[HZc + tid*ZW + z]);
        avb[(2+tid)*10000 + cell] = fminf(fmaxf(sum/5.0f, 0.0f), 1.0f);
    } else if (tid == 16) {
        float agent = 0.0f;
        #pragma unroll
        for (int z = MINZc; z < MAXZc; ++z) agent += rintf(acc[z]);
        float v = fminf(fmaxf(agent, 0.0f), 1.0f);
        avb[0*10000 + cell] = v;
        fp_out[(size_t)b*10000 + cell] = v;
    } else if (tid == 17) {
        float all = 0.0f;
        for (int z = 0; z < HZc; ++z) all += rintf(acc[z]);
        avb[1*10000 + cell] = fminf(fmaxf(all, 0.0f), 1.0f);
    }
}

// ---------------- fused double grid_sample + max ----------------
__device__ __forceinline__ float grid1d(int i) {
    return (float)(-1.0 + (double)i * (2.0/479.0));
}

__global__ void map_kernel(const float* __restrict__ maps_last,
                           const float* __restrict__ avwin,
                           const float* __restrict__ params,
                           float* __restrict__ map_out)
{
    int t = blockIdx.x*blockDim.x + threadIdx.x;
    if (t >= NB*MAPC*MAPC) return;
    int w = t % MAPC;
    int h = (t / MAPC) % MAPC;
    int b = t / (MAPC*MAPC);
    float ct = params[b*4+0], st = params[b*4+1];
    float sx = params[b*4+2], sy = params[b*4+3];

    float xg = grid1d(w) + sx;
    float yg = grid1d(h) + sy;
    float xt = ((xg + 1.0f)*479.0f)/2.0f;
    float yt = ((yg + 1.0f)*479.0f)/2.0f;
    float xf = floorf(xt), yf = floorf(yt);

    float acc[18];
    #pragma unroll
    for (int k=0;k<18;k++) acc[k]=0.0f;
    const float* avb = avwin + (size_t)b*18*10000;

    #pragma unroll
    for (int oy=0; oy<2; ++oy) {
        #pragma unroll
        for (int ox=0; ox<2; ++ox) {
            float qx = xf + (float)ox, qy = yf + (float)oy;
            if (!(qx >= 0.0f && qx < 480.0f && qy >= 0.0f && qy < 480.0f)) continue;
            float wo = (ox ? (xt - xf) : (xf + 1.0f - xt))
                     * (oy ? (yt - yf) : (yf + 1.0f - yt));
            int oxi = (int)qx, oyi = (int)qy;
            float gxr = grid1d(oxi), gyr = grid1d(oyi);
            float xr = ct*gxr - st*gyr;
            float yr = st*gxr + ct*gyr;
            float xp = ((xr + 1.0f)*479.0f)/2.0f;
            float yp = ((yr + 1.0f)*479.0f)/2.0f;
            float xpf = floorf(xp), ypf = floorf(yp);
            float R[18];
            #pragma unroll
            for (int k=0;k<18;k++) R[k]=0.0f;
            #pragma unroll
            for (int iy=0; iy<2; ++iy) {
                #pragma unroll
                for (int ix=0; ix<2; ++ix) {
                    float rx = xpf + (float)ix, ry = ypf + (float)iy;
                    if (!(rx >= 0.0f && rx < 480.0f && ry >= 0.0f && ry < 480.0f)) continue;
                    int rxi = (int)rx, ryi = (int)ry;
                    if (ryi < 240 || ryi >= 340 || rxi < 190 || rxi >= 290) continue;
                    float wi = (ix ? (xp - xpf) : (xpf + 1.0f - xp))
                             * (iy ? (yp - ypf) : (ypf + 1.0f - yp));
                    const float* p = avb + (ryi-240)*VRc + (rxi-190);
                    #pragma unroll
                    for (int k=0;k<18;k++) R[k] += wi * p[k*10000];
                }
            }
            #pragma unroll
            for (int k=0;k<18;k++) acc[k] += wo * R[k];
        }
    }

    #pragma unroll
    for (int c=0;c<COBS;c++) {
        size_t o = (((size_t)b*COBS + c)*MAPC + h)*MAPC + w;
        float tv = (c==0) ? acc[0] : (c==1) ? acc[1] : (c>=4) ? acc[c-2] : 0.0f;
        map_out[o] = fmaxf(maps_last[o], tv);
    }
}

extern "C" void kernel_launch(void* const* d_in, const int* in_sizes, int n_in,
                              void* d_out, int out_size, void* d_ws, size_t ws_size,
                              hipStream_t stream)
{
    const float* obs        = (const float*)d_in[0];
    const float* pose_obs   = (const float*)d_in[1];
    const float* maps_last  = (const float*)d_in[2];
    const float* poses_last = (const float*)d_in[3];
    const float* sh         = (const float*)d_in[4];
    float* out = (float*)d_out;

    float* fp_out  = out;                       // B*1*100*100 = 40000
    float* map_out = out + 40000;               // B*20*480*480 = 18,432,000
    float* poses1  = out + 40000 + 18432000;    // 12
    float* poses2  = poses1 + 12;               // 12

    // d_ws: params + avwin only (proven size)
    float* params = (float*)d_ws;               // 16 floats
    float* avwin  = params + 16;                // B*18*100*100 = 720,000 floats

    // Scratch inside map_out region (fully overwritten by final map_kernel):
    //  payloadPos : 4,915,200 floats
    //  auxBid     : 1,228,800 ints
    //  counts/offsetsWork/countsB/offsetsWorkB : 4 * 40,960 ints = 163,840
    //  bandPos    : BANDMAX*4  = 2,400,000 floats
    //  bandSem    : BANDMAX*16 = 9,600,000 floats
    //  total = 18,307,840 floats <= 18,432,000
    float4* payloadPos  = (float4*)map_out;
    int*    auxBid      = (int*)(map_out + 4915200);
    int*    counts      = (int*)(map_out + 6144000);
    int*    offsetsWork = counts + COUNTS_PAD;
    int*    countsB     = counts + 2*COUNTS_PAD;
    int*    offsetsWorkB= counts + 3*COUNTS_PAD;
    float4* bandPos     = (float4*)(map_out + 6144000 + 4*COUNTS_PAD);
    float4* bandSem     = (float4*)(map_out + 6144000 + 4*COUNTS_PAD + (size_t)BANDMAX*4);

    double rad = 39.5 * 0.017453292519943295;
    float fconst = (float)(320.0 / tan(rad));

    hipLaunchKernelGGL(pose_kernel, dim3(1), dim3(64), 0, stream,
                       pose_obs, poses_last, poses1, poses2, params);

    hipMemsetAsync(counts, 0, (size_t)4*COUNTS_PAD*sizeof(int), stream);

    hipLaunchKernelGGL(bin_count_kernel, dim3((NTOT+255)/256), dim3(256), 0, stream,
                       obs, sh, auxBid, counts, countsB, fconst);

    hipLaunchKernelGGL(scan_kernel, dim3(2), dim3(1024), 0, stream, counts);

    hipLaunchKernelGGL(scatter_kernel, dim3((NTOT+255)/256), dim3(256), 0, stream,
                       obs, sh, auxBid, offsetsWork, offsetsWorkB,
                       payloadPos, bandPos, bandSem, fconst);

    hipLaunchKernelGGL(gather_kernel, dim3(10000, NB), dim3(128), 0, stream,
                       payloadPos, counts, bandPos, bandSem, countsB, avwin, fp_out);

    hipLaunchKernelGGL(map_kernel, dim3((NB*MAPC*MAPC+255)/256), dim3(256), 0, stream,
                       maps_last, avwin, params, map_out);
}